// Round 8
// baseline (122.849 us; speedup 1.0000x reference)
//
#include <hip/hip_runtime.h>
#include <math.h>

#define D 768
#define DF2 384               // D / 2
#define DF4 192               // D / 4
#define NQ 128                // total queries
#define KPQ 784               // keys per query
#define NCHUNK 16             // key chunks per query
#define KCHUNK 49             // KPQ / NCHUNK
#define NCT 6                 // col-tiles (128 cols each)

#define EXP2F(x) __builtin_amdgcn_exp2f(x)

__device__ __forceinline__ float dot4f(const float4 a, const float4 b) {
    return a.x * b.x + a.y * b.y + a.z * b.z + a.w * b.w;
}

// ---------------------------------------------------------------------------
// Transpose Wq, Wv, Wo (768x768) -> ws.  64x64 tiles, LDS +1 pad.
// ---------------------------------------------------------------------------
__global__ __launch_bounds__(256) void k_tr(const float* __restrict__ Wq,
                                            const float* __restrict__ Wv,
                                            const float* __restrict__ Wo,
                                            float* __restrict__ WqT,
                                            float* __restrict__ WvT,
                                            float* __restrict__ WoT) {
    __shared__ float t[64][65];
    const float* src;
    float* dst;
    if (blockIdx.y == 0)      { src = Wq; dst = WqT; }
    else if (blockIdx.y == 1) { src = Wv; dst = WvT; }
    else                      { src = Wo; dst = WoT; }
    const int tr = blockIdx.x / 12, tc = blockIdx.x % 12;
    const int r0 = tr * 64, c0 = tc * 64;
    const int lr = threadIdx.x >> 6, lc = threadIdx.x & 63;
#pragma unroll
    for (int i = 0; i < 16; ++i)
        t[lr + i * 4][lc] = src[(size_t)(r0 + lr + i * 4) * D + c0 + lc];
    __syncthreads();
#pragma unroll
    for (int i = 0; i < 16; ++i)
        dst[(size_t)(c0 + lr + i * 4) * D + r0 + lc] = t[lc][lr + i * 4];
}

// ---------------------------------------------------------------------------
// Fused q + qt-partials.  grid dim3(6, 32), 512 threads.
// Stage A: q[4][d-tile 128] = LR @ WqT + bq  (k_gemm2 structure) -> qbuf.
// Stage B: qt_part[ct][q][e] = sum_{d in d-tile} q[q][d] * Wk[d][e], all e.
// A-broadcasts via uniform VMEM loads of qbuf (L1), never LDS.
// ---------------------------------------------------------------------------
__global__ __launch_bounds__(512) void k_gqqt(const float* __restrict__ LR,
                                              const float2* __restrict__ WqT2,
                                              const float2* __restrict__ bq2,
                                              const float2* __restrict__ Wk2,
                                              float* __restrict__ qbuf,
                                              float2* __restrict__ qtp2) {
    __shared__ float2 part[8][4][64];
    const int ct  = blockIdx.x;          // d-tile 0..5
    const int q0  = blockIdx.y * 4;
    const int tid = threadIdx.x;
    const int wid = __builtin_amdgcn_readfirstlane(tid >> 6);
    const int c2  = tid & 63;

    // ---- stage A: q-slice ----
    {
        const int e2 = ct * 64 + c2;     // float2 col of q (d dimension)
        const float* a0 = LR + (size_t)q0 * D;
        const float* a1 = a0 + D;
        const float* a2 = a1 + D;
        const float* a3 = a2 + D;
        float2 acc0 = {0.f, 0.f}, acc1 = {0.f, 0.f}, acc2 = {0.f, 0.f}, acc3 = {0.f, 0.f};
        const int cbase = wid * 96;
#pragma unroll 8
        for (int i = 0; i < 96; ++i) {
            const int c = cbase + i;
            const float2 wv = WqT2[(size_t)c * DF2 + e2];
            const float x0 = a0[c], x1 = a1[c], x2 = a2[c], x3 = a3[c];
            acc0.x = fmaf(x0, wv.x, acc0.x); acc0.y = fmaf(x0, wv.y, acc0.y);
            acc1.x = fmaf(x1, wv.x, acc1.x); acc1.y = fmaf(x1, wv.y, acc1.y);
            acc2.x = fmaf(x2, wv.x, acc2.x); acc2.y = fmaf(x2, wv.y, acc2.y);
            acc3.x = fmaf(x3, wv.x, acc3.x); acc3.y = fmaf(x3, wv.y, acc3.y);
        }
        part[wid][0][c2] = acc0;
        part[wid][1][c2] = acc1;
        part[wid][2][c2] = acc2;
        part[wid][3][c2] = acc3;
    }
    __syncthreads();
    if (tid < 256) {
        const int q = tid >> 6, c = tid & 63;
        float2 s = {0.f, 0.f};
#pragma unroll
        for (int p = 0; p < 8; ++p) {
            s.x += part[p][q][c].x;
            s.y += part[p][q][c].y;
        }
        const float2 b = bq2[ct * 64 + c];
        s.x += b.x; s.y += b.y;
        *reinterpret_cast<float2*>(&qbuf[(size_t)(q0 + q) * D + (ct * 64 + c) * 2]) = s;
    }
    __syncthreads();   // drains stores; stage B reads the block's own q-slice

    // ---- stage B: qt partials over this block's d-tile ----
    if (wid < 6) {
        const int ee2 = wid * 64 + (tid & 63);   // float2 col of qt output e
        float2 b0 = {0.f, 0.f}, b1 = {0.f, 0.f}, b2 = {0.f, 0.f}, b3 = {0.f, 0.f};
        const int dbase = ct * 128;
        for (int i4 = 0; i4 < 32; ++i4) {
            const int d = dbase + i4 * 4;
            const float4 x0 = *reinterpret_cast<const float4*>(&qbuf[(size_t)(q0 + 0) * D + d]);
            const float4 x1 = *reinterpret_cast<const float4*>(&qbuf[(size_t)(q0 + 1) * D + d]);
            const float4 x2 = *reinterpret_cast<const float4*>(&qbuf[(size_t)(q0 + 2) * D + d]);
            const float4 x3 = *reinterpret_cast<const float4*>(&qbuf[(size_t)(q0 + 3) * D + d]);
#pragma unroll
            for (int k = 0; k < 4; ++k) {
                const float2 wv = Wk2[(size_t)(d + k) * DF2 + ee2];
                const float v0 = (k == 0) ? x0.x : (k == 1) ? x0.y : (k == 2) ? x0.z : x0.w;
                const float v1 = (k == 0) ? x1.x : (k == 1) ? x1.y : (k == 2) ? x1.z : x1.w;
                const float v2 = (k == 0) ? x2.x : (k == 1) ? x2.y : (k == 2) ? x2.z : x2.w;
                const float v3 = (k == 0) ? x3.x : (k == 1) ? x3.y : (k == 2) ? x3.z : x3.w;
                b0.x = fmaf(v0, wv.x, b0.x); b0.y = fmaf(v0, wv.y, b0.y);
                b1.x = fmaf(v1, wv.x, b1.x); b1.y = fmaf(v1, wv.y, b1.y);
                b2.x = fmaf(v2, wv.x, b2.x); b2.y = fmaf(v2, wv.y, b2.y);
                b3.x = fmaf(v3, wv.x, b3.x); b3.y = fmaf(v3, wv.y, b3.y);
            }
        }
        qtp2[(size_t)(ct * NQ + q0 + 0) * DF2 + ee2] = b0;
        qtp2[(size_t)(ct * NQ + q0 + 1) * DF2 + ee2] = b1;
        qtp2[(size_t)(ct * NQ + q0 + 2) * DF2 + ee2] = b2;
        qtp2[(size_t)(ct * NQ + q0 + 3) * DF2 + ee2] = b3;
    }
}

// ---------------------------------------------------------------------------
// Flash pass (no max-tracking; scores tiny).  Prologue sums the 6 qt_part
// slices and scales by 1/sqrt(d)*log2e.  HR read exactly once.
// One block per (query, key-chunk of 49); 4 waves; 2 rows/iter/wave.
// ---------------------------------------------------------------------------
__global__ __launch_bounds__(256) void k_flash(const float4* __restrict__ HR,
                                               const float4* __restrict__ qtp4,
                                               float4* __restrict__ Cpart,
                                               float* __restrict__ Lp) {
    __shared__ __align__(16) float4 qt_lds[DF4];
    const int b     = blockIdx.x;
    const int qi    = b >> 4;
    const int chunk = b & 15;
    const size_t rowbase = (size_t)qi * KPQ + (size_t)chunk * KCHUNK;
    const int tid  = threadIdx.x;
    const int w    = tid >> 6;
    const int lane = tid & 63;

    if (tid < DF4) {
        float4 s = make_float4(0.f, 0.f, 0.f, 0.f);
#pragma unroll
        for (int ct = 0; ct < NCT; ++ct) {
            const float4 v = qtp4[(size_t)(ct * NQ + qi) * DF4 + tid];
            s.x += v.x; s.y += v.y; s.z += v.z; s.w += v.w;
        }
        const float rsd2 = 0.036084391824351615f * 1.4426950408889634f; // 1/sqrt(768)*log2e
        s.x *= rsd2; s.y *= rsd2; s.z *= rsd2; s.w *= rsd2;
        qt_lds[tid] = s;
    }
    __syncthreads();

    const float4 qa = qt_lds[lane];
    const float4 qb = qt_lds[lane + 64];
    const float4 qc = qt_lds[lane + 128];

    float l = 0.f;
    float4 c0 = make_float4(0.f, 0.f, 0.f, 0.f);
    float4 c1 = make_float4(0.f, 0.f, 0.f, 0.f);
    float4 c2 = make_float4(0.f, 0.f, 0.f, 0.f);

    int j = w;
    while (j + 4 < KCHUNK) {
        const float4* rowA = HR + (rowbase + (size_t)j) * DF4;
        const float4* rowB = HR + (rowbase + (size_t)(j + 4)) * DF4;
        const float4 a0 = rowA[lane], a1 = rowA[lane + 64], a2 = rowA[lane + 128];
        const float4 b0 = rowB[lane], b1 = rowB[lane + 64], b2 = rowB[lane + 128];
        float p1 = dot4f(qa, a0) + dot4f(qb, a1) + dot4f(qc, a2);
        float p2 = dot4f(qa, b0) + dot4f(qb, b1) + dot4f(qc, b2);
#pragma unroll
        for (int off = 32; off; off >>= 1) {
            p1 += __shfl_xor(p1, off, 64);
            p2 += __shfl_xor(p2, off, 64);
        }
        const float e1 = EXP2F(p1);
        const float e2 = EXP2F(p2);
        l += e1 + e2;
        c0.x += fmaf(e1, a0.x, e2 * b0.x);
        c0.y += fmaf(e1, a0.y, e2 * b0.y);
        c0.z += fmaf(e1, a0.z, e2 * b0.z);
        c0.w += fmaf(e1, a0.w, e2 * b0.w);
        c1.x += fmaf(e1, a1.x, e2 * b1.x);
        c1.y += fmaf(e1, a1.y, e2 * b1.y);
        c1.z += fmaf(e1, a1.z, e2 * b1.z);
        c1.w += fmaf(e1, a1.w, e2 * b1.w);
        c2.x += fmaf(e1, a2.x, e2 * b2.x);
        c2.y += fmaf(e1, a2.y, e2 * b2.y);
        c2.z += fmaf(e1, a2.z, e2 * b2.z);
        c2.w += fmaf(e1, a2.w, e2 * b2.w);
        j += 8;
    }
    if (j < KCHUNK) {
        const float4* rowA = HR + (rowbase + (size_t)j) * DF4;
        const float4 a0 = rowA[lane], a1 = rowA[lane + 64], a2 = rowA[lane + 128];
        float p1 = dot4f(qa, a0) + dot4f(qb, a1) + dot4f(qc, a2);
#pragma unroll
        for (int off = 32; off; off >>= 1) p1 += __shfl_xor(p1, off, 64);
        const float e1 = EXP2F(p1);
        l += e1;
        c0.x = fmaf(e1, a0.x, c0.x); c0.y = fmaf(e1, a0.y, c0.y);
        c0.z = fmaf(e1, a0.z, c0.z); c0.w = fmaf(e1, a0.w, c0.w);
        c1.x = fmaf(e1, a1.x, c1.x); c1.y = fmaf(e1, a1.y, c1.y);
        c1.z = fmaf(e1, a1.z, c1.z); c1.w = fmaf(e1, a1.w, c1.w);
        c2.x = fmaf(e1, a2.x, c2.x); c2.y = fmaf(e1, a2.y, c2.y);
        c2.z = fmaf(e1, a2.z, c2.z); c2.w = fmaf(e1, a2.w, c2.w);
    }

    __shared__ __align__(16) float4 c_lds[4][DF4];
    __shared__ float l_lds[4];
    c_lds[w][lane]       = c0;
    c_lds[w][lane + 64]  = c1;
    c_lds[w][lane + 128] = c2;
    if (lane == 0) l_lds[w] = l;
    __syncthreads();

    if (tid < DF4) {
        float4 cc = make_float4(0.f, 0.f, 0.f, 0.f);
#pragma unroll
        for (int p = 0; p < 4; ++p) {
            const float4 cv = c_lds[p][tid];
            cc.x += cv.x; cc.y += cv.y; cc.z += cv.z; cc.w += cv.w;
        }
        Cpart[(size_t)b * DF4 + tid] = cc;
        if (tid == 0) Lp[b] = l_lds[0] + l_lds[1] + l_lds[2] + l_lds[3];
    }
}

// ---------------------------------------------------------------------------
// Fused combine + X = (Cn/L) @ WvT + bv.  grid dim3(6, 32), 512 threads.
// Prologue: cn[4][768] = sum_p Cpart -> cnbuf (dup-written by 6 ct-blocks,
// identical values).  GEMM A-broadcasts via uniform VMEM loads of cnbuf;
// 1/L folded into the epilogue (GEMM linearity).
// ---------------------------------------------------------------------------
__global__ __launch_bounds__(512) void k_gemmV(const float4* __restrict__ Cpart4,
                                               const float* __restrict__ Lp,
                                               const float2* __restrict__ WvT2,
                                               const float2* __restrict__ bv2,
                                               float* __restrict__ cnbuf,
                                               float2* __restrict__ Xbuf2) {
    __shared__ float2 part[8][4][64];
    const int ct  = blockIdx.x;
    const int q0  = blockIdx.y * 4;
    const int tid = threadIdx.x;

    // prologue: cn = sum of chunk partials (shared reference 0 -> plain sum)
    for (int f = tid; f < 4 * DF4; f += 512) {
        const int q = f / DF4, ff = f % DF4;
        float4 s = make_float4(0.f, 0.f, 0.f, 0.f);
#pragma unroll
        for (int p = 0; p < NCHUNK; ++p) {
            const float4 v = Cpart4[(size_t)((q0 + q) * NCHUNK + p) * DF4 + ff];
            s.x += v.x; s.y += v.y; s.z += v.z; s.w += v.w;
        }
        *reinterpret_cast<float4*>(&cnbuf[(size_t)(q0 + q) * D + ff * 4]) = s;
    }
    float invL[4];
#pragma unroll
    for (int q = 0; q < 4; ++q) {
        float L = 0.f;
#pragma unroll
        for (int p = 0; p < NCHUNK; ++p) L += Lp[(q0 + q) * NCHUNK + p];
        invL[q] = 1.f / L;
    }
    __syncthreads();   // cnbuf stores drained; GEMM reads block's own writes

    const int wid = __builtin_amdgcn_readfirstlane(tid >> 6);
    const int c2  = tid & 63;
    const int e2  = ct * 64 + c2;
    float2 acc0 = {0.f, 0.f}, acc1 = {0.f, 0.f}, acc2 = {0.f, 0.f}, acc3 = {0.f, 0.f};
    const int dbase = wid * 96;
    for (int i4 = 0; i4 < 24; ++i4) {
        const int d = dbase + i4 * 4;
        const float4 x0 = *reinterpret_cast<const float4*>(&cnbuf[(size_t)(q0 + 0) * D + d]);
        const float4 x1 = *reinterpret_cast<const float4*>(&cnbuf[(size_t)(q0 + 1) * D + d]);
        const float4 x2 = *reinterpret_cast<const float4*>(&cnbuf[(size_t)(q0 + 2) * D + d]);
        const float4 x3 = *reinterpret_cast<const float4*>(&cnbuf[(size_t)(q0 + 3) * D + d]);
#pragma unroll
        for (int k = 0; k < 4; ++k) {
            const float2 wv = WvT2[(size_t)(d + k) * DF2 + e2];
            const float v0 = (k == 0) ? x0.x : (k == 1) ? x0.y : (k == 2) ? x0.z : x0.w;
            const float v1 = (k == 0) ? x1.x : (k == 1) ? x1.y : (k == 2) ? x1.z : x1.w;
            const float v2 = (k == 0) ? x2.x : (k == 1) ? x2.y : (k == 2) ? x2.z : x2.w;
            const float v3 = (k == 0) ? x3.x : (k == 1) ? x3.y : (k == 2) ? x3.z : x3.w;
            acc0.x = fmaf(v0, wv.x, acc0.x); acc0.y = fmaf(v0, wv.y, acc0.y);
            acc1.x = fmaf(v1, wv.x, acc1.x); acc1.y = fmaf(v1, wv.y, acc1.y);
            acc2.x = fmaf(v2, wv.x, acc2.x); acc2.y = fmaf(v2, wv.y, acc2.y);
            acc3.x = fmaf(v3, wv.x, acc3.x); acc3.y = fmaf(v3, wv.y, acc3.y);
        }
    }
    part[wid][0][c2] = acc0;
    part[wid][1][c2] = acc1;
    part[wid][2][c2] = acc2;
    part[wid][3][c2] = acc3;
    __syncthreads();
    if (tid < 256) {
        const int q = tid >> 6, c = tid & 63;
        float2 s = {0.f, 0.f};
#pragma unroll
        for (int p = 0; p < 8; ++p) {
            s.x += part[p][q][c].x;
            s.y += part[p][q][c].y;
        }
        const float2 b = bv2[ct * 64 + c];
        s.x = s.x * invL[q] + b.x;
        s.y = s.y * invL[q] + b.y;
        Xbuf2[(size_t)(q0 + q) * DF2 + ct * 64 + c] = s;
    }
}

// ---------------------------------------------------------------------------
// Small GEMM (gemmO): Out[q][e] = sum_d A[q][d]*W[d][e] + b + res.  Proven R7.
// ---------------------------------------------------------------------------
__global__ __launch_bounds__(512) void k_gemmO(const float* __restrict__ A,
                                               const float2* __restrict__ W2,
                                               const float2* __restrict__ bias2,
                                               const float2* __restrict__ res2,
                                               float2* __restrict__ Out2) {
    __shared__ float2 part[8][4][64];
    const int ct  = blockIdx.x % 6;
    const int q0  = (blockIdx.x / 6) * 4;
    const int tid = threadIdx.x;
    const int ds  = __builtin_amdgcn_readfirstlane(tid >> 6);
    const int c2  = tid & 63;
    const int e2  = ct * 64 + c2;
    const float* a0 = A + (size_t)q0 * D;
    const float* a1 = a0 + D;
    const float* a2 = a1 + D;
    const float* a3 = a2 + D;
    float2 acc0 = {0.f, 0.f}, acc1 = {0.f, 0.f}, acc2 = {0.f, 0.f}, acc3 = {0.f, 0.f};
    const int dbase = ds * 96;
#pragma unroll 8
    for (int i = 0; i < 96; ++i) {
        const int d = dbase + i;
        const float2 wv = W2[(size_t)d * DF2 + e2];
        const float x0 = a0[d], x1 = a1[d], x2 = a2[d], x3 = a3[d];
        acc0.x = fmaf(x0, wv.x, acc0.x); acc0.y = fmaf(x0, wv.y, acc0.y);
        acc1.x = fmaf(x1, wv.x, acc1.x); acc1.y = fmaf(x1, wv.y, acc1.y);
        acc2.x = fmaf(x2, wv.x, acc2.x); acc2.y = fmaf(x2, wv.y, acc2.y);
        acc3.x = fmaf(x3, wv.x, acc3.x); acc3.y = fmaf(x3, wv.y, acc3.y);
    }
    part[ds][0][c2] = acc0;
    part[ds][1][c2] = acc1;
    part[ds][2][c2] = acc2;
    part[ds][3][c2] = acc3;
    __syncthreads();
    if (tid < 256) {
        const int q = tid >> 6, c = tid & 63;
        float2 s = {0.f, 0.f};
#pragma unroll
        for (int p = 0; p < 8; ++p) {
            s.x += part[p][q][c].x;
            s.y += part[p][q][c].y;
        }
        const float2 b = bias2[ct * 64 + c];
        const float2 r = res2[(size_t)(q0 + q) * DF2 + ct * 64 + c];
        s.x += b.x + r.x;
        s.y += b.y + r.y;
        Out2[(size_t)(q0 + q) * DF2 + ct * 64 + c] = s;
    }
}

// ---------------------------------------------------------------------------
// LayerNorm: one block per query (256 threads, 3 elems each).
// ---------------------------------------------------------------------------
__global__ __launch_bounds__(256) void k_ln(const float* __restrict__ y,
                                            const float* __restrict__ gamma,
                                            const float* __restrict__ beta,
                                            float* __restrict__ out) {
    __shared__ float sp[4], ssp[4];
    const int qi = blockIdx.x;
    const int tid = threadIdx.x, w = tid >> 6, lane = tid & 63;
    const float* yr = y + (size_t)qi * D;
    const float v0 = yr[tid], v1 = yr[tid + 256], v2 = yr[tid + 512];
    float s  = v0 + v1 + v2;
    float ss = v0 * v0 + v1 * v1 + v2 * v2;
#pragma unroll
    for (int off = 32; off; off >>= 1) {
        s  += __shfl_xor(s, off, 64);
        ss += __shfl_xor(ss, off, 64);
    }
    if (lane == 0) { sp[w] = s; ssp[w] = ss; }
    __syncthreads();
    s  = sp[0] + sp[1] + sp[2] + sp[3];
    ss = ssp[0] + ssp[1] + ssp[2] + ssp[3];
    const float mu  = s * (1.f / 768.f);
    const float var = ss * (1.f / 768.f) - mu * mu;
    const float rs  = rsqrtf(var + 1e-5f);
    float* o = out + (size_t)qi * D;
    o[tid]       = (v0 - mu) * rs * gamma[tid]       + beta[tid];
    o[tid + 256] = (v1 - mu) * rs * gamma[tid + 256] + beta[tid + 256];
    o[tid + 512] = (v2 - mu) * rs * gamma[tid + 512] + beta[tid + 512];
}

extern "C" void kernel_launch(void* const* d_in, const int* in_sizes, int n_in,
                              void* d_out, int out_size, void* d_ws, size_t ws_size,
                              hipStream_t stream) {
    const float* LR    = (const float*)d_in[0];
    const float* HR    = (const float*)d_in[1];
    const float* Wq    = (const float*)d_in[2];
    const float* bq    = (const float*)d_in[3];
    const float* Wk    = (const float*)d_in[4];
    // d_in[5] = bk: unused (per-query constant on all scores; softmax-invariant)
    const float* Wv    = (const float*)d_in[6];
    const float* bv    = (const float*)d_in[7];
    const float* Wo    = (const float*)d_in[8];
    const float* bo    = (const float*)d_in[9];
    const float* gamma = (const float*)d_in[10];
    const float* beta  = (const float*)d_in[11];
    float* out = (float*)d_out;

    float* ws = (float*)d_ws;
    float* WqT   = ws;                  // 589824
    float* WvT   = ws + 589824;         // 589824
    float* WoT   = ws + 1179648;        // 589824
    float* qbuf  = ws + 1769472;        // 98304
    float* qtp   = ws + 1867776;        // 6*128*768 = 589824
    float* Cpart = ws + 2457600;        // 2048*768 = 1572864
    float* Lp    = ws + 4030464;        // 2048
    float* cnbuf = ws + 4032512;        // 98304
    float* Xbuf  = ws + 4130816;        // 98304
    float* ybuf  = ws + 4229120;        // 98304

    // transpose Wq, Wv, Wo
    k_tr<<<dim3(144, 3), 256, 0, stream>>>(Wq, Wv, Wo, WqT, WvT, WoT);
    // q (full) + qt partials, fused
    k_gqqt<<<dim3(NCT, 32), 512, 0, stream>>>(LR, (const float2*)WqT, (const float2*)bq,
                                              (const float2*)Wk, qbuf, (float2*)qtp);
    // flash pass over HR (prologue sums qt partials)
    k_flash<<<NQ * NCHUNK, 256, 0, stream>>>((const float4*)HR, (const float4*)qtp,
                                             (float4*)Cpart, Lp);
    // combine + X = (Cn/L) @ WvT + bv, fused
    k_gemmV<<<dim3(NCT, 32), 512, 0, stream>>>((const float4*)Cpart, Lp,
                                               (const float2*)WvT, (const float2*)bv,
                                               cnbuf, (float2*)Xbuf);
    // y = q + X @ WoT + bo
    k_gemmO<<<192, 512, 0, stream>>>(Xbuf, (const float2*)WoT, (const float2*)bo,
                                     (const float2*)qbuf, (float2*)ybuf);
    // LayerNorm
    k_ln<<<NQ, 256, 0, stream>>>(ybuf, gamma, beta, out);
}